// Round 5
// baseline (89.851 us; speedup 1.0000x reference)
//
#include <hip/hip_runtime.h>
#include <hip/hip_fp16.h>
#include <math.h>

#define NEG_INF_F (-1e30f)
#define LRELU 0.2f

constexpr int Bb = 64, Ee = 512, IND = 1024, OUTD = 256;
constexpr int Mrows = Bb * Ee; // 32768

typedef __attribute__((ext_vector_type(8))) _Float16 half8;
typedef __attribute__((ext_vector_type(4))) _Float16 half4;
typedef __attribute__((ext_vector_type(4))) float floatx4;

#define AS1 __attribute__((address_space(1)))
#define AS3 __attribute__((address_space(3)))

// ---------------- Kernel 0: W fp32 -> fp16 ----------------
__global__ __launch_bounds__(256) void wconv_kernel(
    const float* __restrict__ W, _Float16* __restrict__ Whf)
{
    const int i = (blockIdx.x * 256 + threadIdx.x) * 4;
    const float4 w = *reinterpret_cast<const float4*>(&W[i]);
    half4 hh;
    hh[0] = (_Float16)w.x; hh[1] = (_Float16)w.y;
    hh[2] = (_Float16)w.z; hh[3] = (_Float16)w.w;
    *reinterpret_cast<half4*>(&Whf[i]) = hh;
}

// ---------------- Kernel 1: H = X @ W^T + b, counted-vmcnt pipelined MFMA ----
// BM=128, BN=256(full), BK=64, 512 thr = 8 waves (2x4), wave tile 64x64.
// B: triple-buffered LDS via global_load_lds, depth-2 prefetch.
// A: reg-staged depth-2 (2 static reg sets), fp32->fp16 convert, ds_write.
// Steady-state barrier wait: vmcnt(8) -- 8 VMEM stay in flight across barriers.
__global__ __launch_bounds__(512, 2) void gemm_h_f16(
    const float* __restrict__ X, const _Float16* __restrict__ Whf,
    const float* __restrict__ Wb, const float* __restrict__ aw,
    const int* __restrict__ mask,
    _Float16* __restrict__ HmTh, _Float16* __restrict__ HmTl,
    float* __restrict__ s1, float* __restrict__ s2)
{
    __shared__ char lds_raw[135680];
    _Float16* As = (_Float16*)lds_raw;            // [2][128][64] halves, 32 KB
    _Float16* Bs = (_Float16*)(lds_raw + 32768);  // [3][256][64] halves, 96 KB
    // epilogue overlays:
    _Float16* Th = (_Float16*)lds_raw;            // [256][128] 64 KB
    _Float16* Tl = (_Float16*)(lds_raw + 65536);  // 64 KB
    float* s1p  = (float*)(lds_raw + 131072);     // [4][128]
    float* s2p  = (float*)(lds_raw + 133120);     // [4][128]
    float* mkfs = (float*)(lds_raw + 135168);     // [128]

    const int tid = threadIdx.x;
    const int w  = tid >> 6, l = tid & 63, ln = l & 15, lg = l >> 4;
    const int wr = w >> 2, wc = w & 3;
    const int m0 = blockIdx.x * 128;

    // A staging: thread -> row arow, 16-float chunk at ak
    const int arow = tid >> 2, ak = (tid & 3) * 16;
    const float* __restrict__ xp = X + (size_t)(m0 + arow) * IND + ak;

    // B gload source mapping (pre-swizzled global source, linear LDS dest)
    const int brow_base = w * 32;
    const int bsub = l >> 3;            // 0..7
    const int bch  = (l & 7) ^ bsub;    // swizzled source chunk

    floatx4 acc[4][4];
    #pragma unroll
    for (int i = 0; i < 4; ++i)
        #pragma unroll
        for (int j = 0; j < 4; ++j)
            acc[i][j] = (floatx4)0.f;

    int bB0 = 0, bB1 = 1, bB2 = 2;

    auto stageB = [&](int kc, int bufB) {
        #pragma unroll
        for (int j = 0; j < 4; ++j) {
            const size_t src = (size_t)(brow_base + j * 8 + bsub) * IND + kc * 64 + bch * 8;
            __builtin_amdgcn_global_load_lds(
                (const AS1 unsigned int*)(Whf + src),
                (AS3 unsigned int*)(Bs + bufB * 16384 + (brow_base + j * 8) * 64),
                16, 0, 0);
        }
    };
    auto writeA = [&](int abuf, const float4& r0, const float4& r1,
                      const float4& r2, const float4& r3) {
        half8 h0, h1;
        h0[0] = (_Float16)r0.x; h0[1] = (_Float16)r0.y;
        h0[2] = (_Float16)r0.z; h0[3] = (_Float16)r0.w;
        h0[4] = (_Float16)r1.x; h0[5] = (_Float16)r1.y;
        h0[6] = (_Float16)r1.z; h0[7] = (_Float16)r1.w;
        h1[0] = (_Float16)r2.x; h1[1] = (_Float16)r2.y;
        h1[2] = (_Float16)r2.z; h1[3] = (_Float16)r2.w;
        h1[4] = (_Float16)r3.x; h1[5] = (_Float16)r3.y;
        h1[6] = (_Float16)r3.z; h1[7] = (_Float16)r3.w;
        const int c0 = (tid & 3) * 2;
        *reinterpret_cast<half8*>(As + abuf * 8192 + arow * 64 + ((c0    ) ^ (arow & 7)) * 8) = h0;
        *reinterpret_cast<half8*>(As + abuf * 8192 + arow * 64 + ((c0 + 1) ^ (arow & 7)) * 8) = h1;
    };

    float4 xa0, xa1, xa2, xa3, xb0, xb1, xb2, xb3;

    // ---- prologue: A0 -> As[0] direct; A1 -> regs(xb); B0 -> Bs[0]; B1 -> Bs[1]
    {
        const float4 p0 = *reinterpret_cast<const float4*>(xp + 0);
        const float4 p1 = *reinterpret_cast<const float4*>(xp + 4);
        const float4 p2 = *reinterpret_cast<const float4*>(xp + 8);
        const float4 p3 = *reinterpret_cast<const float4*>(xp + 12);
        xb0 = *reinterpret_cast<const float4*>(xp + 64);
        xb1 = *reinterpret_cast<const float4*>(xp + 68);
        xb2 = *reinterpret_cast<const float4*>(xp + 72);
        xb3 = *reinterpret_cast<const float4*>(xp + 76);
        stageB(0, 0);
        stageB(1, 1);
        writeA(0, p0, p1, p2, p3);
        asm volatile("s_waitcnt vmcnt(4) lgkmcnt(0)" ::: "memory");
        __builtin_amdgcn_sched_barrier(0);
        __builtin_amdgcn_s_barrier();
        __builtin_amdgcn_sched_barrier(0);
    }

    auto body = [&](int t,
                    float4& L0, float4& L1, float4& L2, float4& L3,   // load chunk t+2
                    const float4& C0, const float4& C1,
                    const float4& C2, const float4& C3) {             // holds chunk t+1
        // ---- phase 1: issue prefetches (depth-2) ----
        if (t < 14) {
            const float* xq = xp + (t + 2) * 64;
            L0 = *reinterpret_cast<const float4*>(xq + 0);
            L1 = *reinterpret_cast<const float4*>(xq + 4);
            L2 = *reinterpret_cast<const float4*>(xq + 8);
            L3 = *reinterpret_cast<const float4*>(xq + 12);
            stageB(t + 2, bB2);
        }
        __builtin_amdgcn_sched_barrier(0);

        // ---- phase 2+3: ds_read fragments + MFMA ----
        const int abuf = t & 1;
        #pragma unroll
        for (int kk = 0; kk < 2; ++kk) {
            half8 af[4], bf[4];
            #pragma unroll
            for (int mr = 0; mr < 4; ++mr)
                af[mr] = *reinterpret_cast<const half8*>(
                    As + abuf * 8192 + (wr * 64 + mr * 16 + ln) * 64 + (((kk * 4 + lg) ^ (ln & 7)) * 8));
            #pragma unroll
            for (int nr = 0; nr < 4; ++nr)
                bf[nr] = *reinterpret_cast<const half8*>(
                    Bs + bB0 * 16384 + (wc * 64 + nr * 16 + ln) * 64 + (((kk * 4 + lg) ^ (ln & 7)) * 8));
            __builtin_amdgcn_s_setprio(1);
            #pragma unroll
            for (int mr = 0; mr < 4; ++mr)
                #pragma unroll
                for (int nr = 0; nr < 4; ++nr)
                    acc[mr][nr] = __builtin_amdgcn_mfma_f32_16x16x32_f16(
                        af[mr], bf[nr], acc[mr][nr], 0, 0, 0);
            __builtin_amdgcn_s_setprio(0);
        }

        // ---- phase 4: convert & publish A(t+1); counted-vmcnt barrier ----
        if (t < 15) writeA((t + 1) & 1, C0, C1, C2, C3);
        if (t < 14) asm volatile("s_waitcnt vmcnt(8) lgkmcnt(0)" ::: "memory");
        else        asm volatile("s_waitcnt vmcnt(0) lgkmcnt(0)" ::: "memory");
        __builtin_amdgcn_sched_barrier(0);
        __builtin_amdgcn_s_barrier();
        __builtin_amdgcn_sched_barrier(0);
        const int tmp = bB0; bB0 = bB1; bB1 = bB2; bB2 = tmp;
    };

    for (int p = 0; p < 8; ++p) {
        body(2 * p,     xa0, xa1, xa2, xa3, xb0, xb1, xb2, xb3);
        body(2 * p + 1, xb0, xb1, xb2, xb3, xa0, xa1, xa2, xa3);
    }

    // ---- epilogue ----
    __syncthreads();
    if (tid < 128) mkfs[tid] = (float)mask[m0 + tid];

    float bias[4], a1c[4], a2c[4];
    #pragma unroll
    for (int nr = 0; nr < 4; ++nr) {
        const int n = wc * 64 + nr * 16 + ln;
        bias[nr] = Wb[n];
        a1c[nr]  = aw[n];
        a2c[nr]  = aw[OUTD + n];
    }
    float sv1[4][4], sv2[4][4];
    #pragma unroll
    for (int i = 0; i < 4; ++i)
        #pragma unroll
        for (int r = 0; r < 4; ++r) { sv1[i][r] = 0.f; sv2[i][r] = 0.f; }

    #pragma unroll
    for (int mr = 0; mr < 4; ++mr)
        #pragma unroll
        for (int nr = 0; nr < 4; ++nr) {
            const int o = wc * 64 + nr * 16 + ln;
            half4 hh, hl;
            #pragma unroll
            for (int rr = 0; rr < 4; ++rr) {
                const float hb = acc[mr][nr][rr] + bias[nr];
                sv1[mr][rr] += hb * a1c[nr];
                sv2[mr][rr] += hb * a2c[nr];
                const _Float16 hhi = (_Float16)hb;
                hh[rr] = hhi;
                hl[rr] = (_Float16)(hb - (float)hhi);
            }
            const int ebase = wr * 64 + mr * 16 + lg * 4;
            const int idx = o * 128 + (ebase ^ ((o & 7) << 3));
            *reinterpret_cast<half4*>(Th + idx) = hh;
            *reinterpret_cast<half4*>(Tl + idx) = hl;
        }

    #pragma unroll
    for (int mr = 0; mr < 4; ++mr)
        #pragma unroll
        for (int rr = 0; rr < 4; ++rr) {
            float v1 = sv1[mr][rr], v2 = sv2[mr][rr];
            #pragma unroll
            for (int off = 1; off < 16; off <<= 1) {
                v1 += __shfl_xor(v1, off, 64);
                v2 += __shfl_xor(v2, off, 64);
            }
            if (ln == 0) {
                const int e = wr * 64 + mr * 16 + lg * 4 + rr;
                s1p[wc * 128 + e] = v1;
                s2p[wc * 128 + e] = v2;
            }
        }
    __syncthreads();

    if (tid < 128) {
        s1[m0 + tid] = s1p[tid] + s1p[128 + tid] + s1p[256 + tid] + s1p[384 + tid];
        s2[m0 + tid] = s2p[tid] + s2p[128 + tid] + s2p[256 + tid] + s2p[384 + tid];
    }

    // coalesced masked HmT store: 256B contiguous per o-row
    const int bIdx = m0 >> 9;
    const int e0   = m0 & 511;
    const int eo4  = (tid & 31) * 4;
    const float q0 = mkfs[eo4 + 0], q1 = mkfs[eo4 + 1];
    const float q2 = mkfs[eo4 + 2], q3 = mkfs[eo4 + 3];
    #pragma unroll
    for (int it = 0; it < 16; ++it) {
        const int o = it * 16 + (tid >> 5);
        const int src = o * 128 + (eo4 ^ ((o & 7) << 3));
        half4 vh = *reinterpret_cast<const half4*>(Th + src);
        half4 vl = *reinterpret_cast<const half4*>(Tl + src);
        if (!(q0 > 0.f)) { vh[0] = (_Float16)0.f; vl[0] = (_Float16)0.f; }
        if (!(q1 > 0.f)) { vh[1] = (_Float16)0.f; vl[1] = (_Float16)0.f; }
        if (!(q2 > 0.f)) { vh[2] = (_Float16)0.f; vl[2] = (_Float16)0.f; }
        if (!(q3 > 0.f)) { vh[3] = (_Float16)0.f; vl[3] = (_Float16)0.f; }
        const size_t goff = ((size_t)(bIdx * OUTD + o) << 9) + e0 + eo4;
        *reinterpret_cast<half4*>(&HmTh[goff]) = vh;
        *reinterpret_cast<half4*>(&HmTl[goff]) = vl;
    }
}

// ---------------- Kernel 2: out[b] = softmax(scores[b]) @ (H[b]*m), MFMA ----
__global__ __launch_bounds__(256, 2) void attn_mfma(
    const _Float16* __restrict__ HmTh, const _Float16* __restrict__ HmTl,
    const float* __restrict__ s1, const float* __restrict__ s2,
    const int* __restrict__ mask, const float* __restrict__ ab_ptr,
    float* __restrict__ Out)
{
    __shared__ float s2v[Ee];
    __shared__ float mkv[Ee];
    __shared__ float rowc[64];
    __shared__ float rmax[64];
    __shared__ int   rvv[64];
    __shared__ _Float16 Pl[2][64][32];
    __shared__ float Zp[64][4];
    __shared__ float zr[64];
    __shared__ float wmax[4];

    const int bid = blockIdx.x;
    const int b  = bid & 63;
    const int i0 = (bid >> 6) * 64;
    const int t  = threadIdx.x;
    const int w  = t >> 6, l = t & 63, ln = l & 15, lg = l >> 4;
    const float ab = ab_ptr[0];

    float lmax = -INFINITY;
    #pragma unroll
    for (int q = 0; q < 2; ++q) {
        const int j = t + q * 256;
        const float sv = s2[b * Ee + j];
        const float mv = (float)mask[b * Ee + j];
        s2v[j] = sv; mkv[j] = mv;
        if (mv > 0.f) lmax = fmaxf(lmax, sv);
    }
    #pragma unroll
    for (int off = 32; off; off >>= 1) lmax = fmaxf(lmax, __shfl_xor(lmax, off, 64));
    if (l == 0) wmax[w] = lmax;
    __syncthreads();
    const float s2max = fmaxf(fmaxf(wmax[0], wmax[1]), fmaxf(wmax[2], wmax[3]));
    const int anyvalid = (s2max > -1e37f) ? 1 : 0;
    if (t < 64) {
        const float c = s1[b * Ee + i0 + t] + ab;
        rowc[t] = c;
        const int mi = mask[b * Ee + i0 + t];
        rvv[t] = (mi != 0) & anyvalid;
        const float rm = c + s2max;
        rmax[t] = (rm >= 0.f) ? rm : LRELU * rm;
    }
    __syncthreads();

    const int pi = t >> 2;
    const int pj = (t & 3) * 8;
    const float prc = rowc[pi];
    const float prm = rmax[pi];
    const int   prv = rvv[pi];
    float zacc = 0.f;

    const size_t obase = (size_t)b * OUTD * Ee;
    const int o0 = w * 64;

    floatx4 acc[4][4];
    #pragma unroll
    for (int i = 0; i < 4; ++i)
        #pragma unroll
        for (int j = 0; j < 4; ++j)
            acc[i][j] = (floatx4)0.f;

    for (int ks = 0; ks < 16; ++ks) {
        const int k0  = ks * 32;
        const int buf = ks & 1;

        half8 ph;
        #pragma unroll
        for (int kk = 0; kk < 8; ++kk) {
            const int j = k0 + pj + kk;
            float pv;
            if (prv) {
                float sc = prc + s2v[j];
                sc = (sc >= 0.f) ? sc : LRELU * sc;
                pv = (mkv[j] > 0.f) ? __expf(sc - prm) : 0.f;
            } else {
                pv = 1.f;
            }
            const _Float16 hq = (_Float16)pv;
            ph[kk] = hq;
            zacc += (float)hq;
        }
        *reinterpret_cast<half8*>(&Pl[buf][pi][pj]) = ph;

        half8 bh[4], bl[4];
        #pragma unroll
        for (int ot = 0; ot < 4; ++ot) {
            const size_t ro = obase + (size_t)(o0 + ot * 16 + ln) * Ee + k0 + lg * 8;
            bh[ot] = *reinterpret_cast<const half8*>(&HmTh[ro]);
            bl[ot] = *reinterpret_cast<const half8*>(&HmTl[ro]);
        }
        __syncthreads();

        half8 af[4];
        #pragma unroll
        for (int mr = 0; mr < 4; ++mr)
            af[mr] = *reinterpret_cast<const half8*>(&Pl[buf][mr * 16 + ln][lg * 8]);
        #pragma unroll
        for (int mr = 0; mr < 4; ++mr)
            #pragma unroll
            for (int ot = 0; ot < 4; ++ot) {
                acc[mr][ot] = __builtin_amdgcn_mfma_f32_16x16x32_f16(
                    af[mr], bh[ot], acc[mr][ot], 0, 0, 0);
                acc[mr][ot] = __builtin_amdgcn_mfma_f32_16x16x32_f16(
                    af[mr], bl[ot], acc[mr][ot], 0, 0, 0);
            }
    }

    Zp[pi][t & 3] = zacc;
    __syncthreads();
    if (t < 64) {
        const float z = Zp[t][0] + Zp[t][1] + Zp[t][2] + Zp[t][3];
        zr[t] = 1.f / z;
    }
    __syncthreads();

    float* __restrict__ Ob = Out + ((size_t)b * Ee + i0) * OUTD;
    #pragma unroll
    for (int mr = 0; mr < 4; ++mr)
        #pragma unroll
        for (int rr = 0; rr < 4; ++rr) {
            const int i = mr * 16 + lg * 4 + rr;
            const float rzi = zr[i];
            #pragma unroll
            for (int ot = 0; ot < 4; ++ot)
                Ob[(size_t)i * OUTD + o0 + ot * 16 + ln] = acc[mr][ot][rr] * rzi;
        }
}

extern "C" void kernel_launch(void* const* d_in, const int* in_sizes, int n_in,
                              void* d_out, int out_size, void* d_ws, size_t ws_size,
                              hipStream_t stream) {
    const float* X    = (const float*)d_in[0];
    // d_in[1] = adj : unused by the reference (dead input)
    const int*   mask = (const int*)d_in[2];
    const float* Ww   = (const float*)d_in[3];
    const float* Wb   = (const float*)d_in[4];
    const float* aw   = (const float*)d_in[5];
    const float* ab   = (const float*)d_in[6];
    float* out = (float*)d_out;

    _Float16* HmTh = (_Float16*)d_ws;                     // 16 MB
    _Float16* HmTl = HmTh + (size_t)Bb * OUTD * Ee;       // 16 MB
    float* s1 = (float*)(HmTl + (size_t)Bb * OUTD * Ee);  // 128 KB
    float* s2 = s1 + Mrows;                               // 128 KB
    _Float16* Whf = (_Float16*)(s2 + Mrows);              // 512 KB

    wconv_kernel<<<OUTD * IND / (256 * 4), 256, 0, stream>>>(Ww, Whf);
    gemm_h_f16<<<Mrows / 128, 512, 0, stream>>>(X, Whf, Wb, aw, mask,
                                                HmTh, HmTl, s1, s2);
    attn_mfma<<<Bb * (Ee / 64), 256, 0, stream>>>(HmTh, HmTl, s1, s2, mask, ab, out);
}

// Round 6
// 73.307 us; speedup vs baseline: 1.2257x; 1.2257x over previous
//
#include <hip/hip_runtime.h>
#include <hip/hip_fp16.h>
#include <math.h>

#define NEG_INF_F (-1e30f)
#define LRELU 0.2f

constexpr int Bb = 64, Ee = 512, IND = 1024, OUTD = 256;
constexpr int Mrows = Bb * Ee; // 32768

typedef __attribute__((ext_vector_type(8))) _Float16 half8;
typedef __attribute__((ext_vector_type(4))) _Float16 half4;
typedef __attribute__((ext_vector_type(4))) float floatx4;

#define AS1 __attribute__((address_space(1)))
#define AS3 __attribute__((address_space(3)))

// ---------------- Kernel 0: W fp32 -> fp16 ----------------
__global__ __launch_bounds__(256) void wconv_kernel(
    const float* __restrict__ W, _Float16* __restrict__ Whf)
{
    const int i = (blockIdx.x * 256 + threadIdx.x) * 4;
    const float4 w = *reinterpret_cast<const float4*>(&W[i]);
    half4 hh;
    hh[0] = (_Float16)w.x; hh[1] = (_Float16)w.y;
    hh[2] = (_Float16)w.z; hh[3] = (_Float16)w.w;
    *reinterpret_cast<half4*>(&Whf[i]) = hh;
}

// ---------------- Kernel 1: H = X @ W^T + b ----------------
// BM=64, BN=256(full), BK=32, 256 thr = 4 waves, wave tile 64x64.
// ALL staging via global_load_lds (A as raw fp32, converted at frag build;
// B fp16). Triple-buffered, counted vmcnt(6), one barrier per step.
// No register-staged loads in the K-loop => no compiler-inserted vmcnt drains.
__global__ __launch_bounds__(256, 2) void gemm_h_f16(
    const float* __restrict__ X, const _Float16* __restrict__ Whf,
    const float* __restrict__ Wb, const float* __restrict__ aw,
    const int* __restrict__ mask,
    _Float16* __restrict__ HmTh, float* __restrict__ s1, float* __restrict__ s2)
{
    __shared__ char lds_raw[73728];
    float*    Af  = (float*)lds_raw;               // [3][64][32] fp32, 24 KB
    _Float16* Bf  = (_Float16*)(lds_raw + 24576);  // [3][256][32] fp16, 48 KB
    // epilogue overlays:
    _Float16* Th   = (_Float16*)lds_raw;           // [256][64] 32 KB
    float*    s1p  = (float*)(lds_raw + 32768);    // [4][64]
    float*    s2p  = (float*)(lds_raw + 33792);    // [4][64]
    float*    mkfs = (float*)(lds_raw + 34816);    // [64]

    const int t  = threadIdx.x;
    const int w  = t >> 6, l = t & 63, ln = l & 15, lg = l >> 4;
    const int m0 = blockIdx.x * 64;

    // A stage: 2 instrs/wave, instr i covers rows (w*2+i)*8..+8 (1 KB each).
    // LDS dest linear; source pre-swizzled: logical fp32-granule = (l&7)^(l>>3).
    const int arl = l >> 3;                 // row within 8-row group
    const int agl = (l & 7) ^ arl;          // logical 16B granule (4 fp32)
    // B stage: 4 instrs/wave, instr i covers rows w*64+i*16..+16 (1 KB each).
    const int brl = l >> 2;                 // row within 16-row group
    const int bgl = (l & 3) ^ ((l >> 3) & 3); // logical 16B granule (8 halves)

    floatx4 acc[4][4];
    #pragma unroll
    for (int i = 0; i < 4; ++i)
        #pragma unroll
        for (int j = 0; j < 4; ++j)
            acc[i][j] = (floatx4)0.f;

    auto stageA = [&](int kc, int aoff) {
        #pragma unroll
        for (int i = 0; i < 2; ++i) {
            const int rbase = (w * 2 + i) * 8;
            const size_t src = (size_t)(m0 + rbase + arl) * IND + kc * 32 + agl * 4;
            __builtin_amdgcn_global_load_lds(
                (const AS1 unsigned int*)(X + src),
                (AS3 unsigned int*)(Af + aoff + rbase * 32), 16, 0, 0);
        }
    };
    auto stageB = [&](int kc, int boff) {
        #pragma unroll
        for (int i = 0; i < 4; ++i) {
            const int nbase = w * 64 + i * 16;
            const size_t src = (size_t)(nbase + brl) * IND + kc * 32 + bgl * 8;
            __builtin_amdgcn_global_load_lds(
                (const AS1 unsigned int*)(Whf + src),
                (AS3 unsigned int*)(Bf + boff + nbase * 32), 16, 0, 0);
        }
    };

    // buffer offsets (elements): rotate {cur, next, stagetgt}
    int aO0 = 0, aO1 = 2048, aO2 = 4096;
    int bO0 = 0, bO1 = 8192, bO2 = 16384;

    // ---- prologue: stage k0 -> slot0, k1 -> slot1 ----
    stageA(0, aO0); stageB(0, bO0);
    stageA(1, aO1); stageB(1, bO1);
    asm volatile("s_waitcnt vmcnt(6) lgkmcnt(0)" ::: "memory"); // k0 complete
    __builtin_amdgcn_sched_barrier(0);
    __builtin_amdgcn_s_barrier();
    __builtin_amdgcn_sched_barrier(0);

    for (int ts = 0; ts < 32; ++ts) {
        // stage k(ts+2) into slot2
        if (ts < 30) { stageA(ts + 2, aO2); stageB(ts + 2, bO2); }
        __builtin_amdgcn_sched_barrier(0);

        // ---- fragments from slot0 ----
        half8 bfrag[4];
        #pragma unroll
        for (int nr = 0; nr < 4; ++nr) {
            const int n = w * 64 + nr * 16 + ln;
            const int phys = lg ^ ((n >> 1) & 3);
            bfrag[nr] = *reinterpret_cast<const half8*>(Bf + bO0 + n * 32 + phys * 8);
        }
        half8 afrag[4];
        #pragma unroll
        for (int mr = 0; mr < 4; ++mr) {
            const int r = mr * 16 + ln;
            const int g0 = (lg * 2) ^ (r & 7);
            const int g1 = (lg * 2 + 1) ^ (r & 7);
            const floatx4 a0 = *reinterpret_cast<const floatx4*>(Af + aO0 + r * 32 + g0 * 4);
            const floatx4 a1 = *reinterpret_cast<const floatx4*>(Af + aO0 + r * 32 + g1 * 4);
            half8 h;
            h[0] = (_Float16)a0[0]; h[1] = (_Float16)a0[1];
            h[2] = (_Float16)a0[2]; h[3] = (_Float16)a0[3];
            h[4] = (_Float16)a1[0]; h[5] = (_Float16)a1[1];
            h[6] = (_Float16)a1[2]; h[7] = (_Float16)a1[3];
            afrag[mr] = h;
        }

        __builtin_amdgcn_s_setprio(1);
        #pragma unroll
        for (int mr = 0; mr < 4; ++mr)
            #pragma unroll
            for (int nr = 0; nr < 4; ++nr)
                acc[mr][nr] = __builtin_amdgcn_mfma_f32_16x16x32_f16(
                    afrag[mr], bfrag[nr], acc[mr][nr], 0, 0, 0);
        __builtin_amdgcn_s_setprio(0);

        // counted wait: drain only the PREVIOUS step's stage (slot1 ready)
        if (ts < 29) asm volatile("s_waitcnt vmcnt(6) lgkmcnt(0)" ::: "memory");
        else         asm volatile("s_waitcnt vmcnt(0) lgkmcnt(0)" ::: "memory");
        __builtin_amdgcn_sched_barrier(0);
        __builtin_amdgcn_s_barrier();
        __builtin_amdgcn_sched_barrier(0);

        int tmp = aO0; aO0 = aO1; aO1 = aO2; aO2 = tmp;
        tmp = bO0; bO0 = bO1; bO1 = bO2; bO2 = tmp;
    }

    // ---- epilogue ----
    if (t < 64) mkfs[t] = (float)mask[m0 + t];

    float bias[4], a1c[4], a2c[4];
    #pragma unroll
    for (int nr = 0; nr < 4; ++nr) {
        const int n = w * 64 + nr * 16 + ln;
        bias[nr] = Wb[n];
        a1c[nr]  = aw[n];
        a2c[nr]  = aw[OUTD + n];
    }
    float sv1[4][4], sv2[4][4];
    #pragma unroll
    for (int i = 0; i < 4; ++i)
        #pragma unroll
        for (int r = 0; r < 4; ++r) { sv1[i][r] = 0.f; sv2[i][r] = 0.f; }

    #pragma unroll
    for (int mr = 0; mr < 4; ++mr)
        #pragma unroll
        for (int nr = 0; nr < 4; ++nr) {
            const int o = w * 64 + nr * 16 + ln;
            half4 hh;
            #pragma unroll
            for (int rr = 0; rr < 4; ++rr) {
                const float hb = acc[mr][nr][rr] + bias[nr];
                sv1[mr][rr] += hb * a1c[nr];
                sv2[mr][rr] += hb * a2c[nr];
                hh[rr] = (_Float16)hb;
            }
            const int e = mr * 16 + lg * 4;
            *reinterpret_cast<half4*>(Th + o * 64 + (e ^ ((o & 7) << 3))) = hh;
        }

    #pragma unroll
    for (int mr = 0; mr < 4; ++mr)
        #pragma unroll
        for (int rr = 0; rr < 4; ++rr) {
            float v1 = sv1[mr][rr], v2 = sv2[mr][rr];
            #pragma unroll
            for (int off = 1; off < 16; off <<= 1) {
                v1 += __shfl_xor(v1, off, 64);
                v2 += __shfl_xor(v2, off, 64);
            }
            if (ln == 0) {
                const int e = mr * 16 + lg * 4 + rr;
                s1p[w * 64 + e] = v1;
                s2p[w * 64 + e] = v2;
            }
        }
    __syncthreads();

    if (t < 64) {
        s1[m0 + t] = s1p[t] + s1p[64 + t] + s1p[128 + t] + s1p[192 + t];
        s2[m0 + t] = s2p[t] + s2p[64 + t] + s2p[128 + t] + s2p[192 + t];
    }

    // coalesced masked HmT store: 128B contiguous per 16-lane group
    const int bIdx = m0 >> 9;
    const int e0   = m0 & 511;
    const int e4   = (t & 15) * 4;
    const float q0 = mkfs[e4 + 0], q1 = mkfs[e4 + 1];
    const float q2 = mkfs[e4 + 2], q3 = mkfs[e4 + 3];
    #pragma unroll
    for (int it = 0; it < 16; ++it) {
        const int o = it * 16 + (t >> 4);
        half4 vh = *reinterpret_cast<const half4*>(Th + o * 64 + (e4 ^ ((o & 7) << 3)));
        if (!(q0 > 0.f)) vh[0] = (_Float16)0.f;
        if (!(q1 > 0.f)) vh[1] = (_Float16)0.f;
        if (!(q2 > 0.f)) vh[2] = (_Float16)0.f;
        if (!(q3 > 0.f)) vh[3] = (_Float16)0.f;
        const size_t goff = ((size_t)(bIdx * OUTD + o) << 9) + e0 + e4;
        *reinterpret_cast<half4*>(&HmTh[goff]) = vh;
    }
}

// ---------------- Kernel 2: out[b] = softmax(scores[b]) @ (H[b]*m), MFMA ----
__global__ __launch_bounds__(256, 2) void attn_mfma(
    const _Float16* __restrict__ HmTh,
    const float* __restrict__ s1, const float* __restrict__ s2,
    const int* __restrict__ mask, const float* __restrict__ ab_ptr,
    float* __restrict__ Out)
{
    __shared__ float s2v[Ee];
    __shared__ float mkv[Ee];
    __shared__ float rowc[64];
    __shared__ float rmax[64];
    __shared__ int   rvv[64];
    __shared__ _Float16 Pl[2][64][32];
    __shared__ float Zp[64][4];
    __shared__ float zr[64];
    __shared__ float wmax[4];

    const int bid = blockIdx.x;
    const int b  = bid & 63;
    const int i0 = (bid >> 6) * 64;
    const int t  = threadIdx.x;
    const int w  = t >> 6, l = t & 63, ln = l & 15, lg = l >> 4;
    const float ab = ab_ptr[0];

    float lmax = -INFINITY;
    #pragma unroll
    for (int q = 0; q < 2; ++q) {
        const int j = t + q * 256;
        const float sv = s2[b * Ee + j];
        const float mv = (float)mask[b * Ee + j];
        s2v[j] = sv; mkv[j] = mv;
        if (mv > 0.f) lmax = fmaxf(lmax, sv);
    }
    #pragma unroll
    for (int off = 32; off; off >>= 1) lmax = fmaxf(lmax, __shfl_xor(lmax, off, 64));
    if (l == 0) wmax[w] = lmax;
    __syncthreads();
    const float s2max = fmaxf(fmaxf(wmax[0], wmax[1]), fmaxf(wmax[2], wmax[3]));
    const int anyvalid = (s2max > -1e37f) ? 1 : 0;
    if (t < 64) {
        const float c = s1[b * Ee + i0 + t] + ab;
        rowc[t] = c;
        const int mi = mask[b * Ee + i0 + t];
        rvv[t] = (mi != 0) & anyvalid;
        const float rm = c + s2max;
        rmax[t] = (rm >= 0.f) ? rm : LRELU * rm;
    }
    __syncthreads();

    const int pi = t >> 2;
    const int pj = (t & 3) * 8;
    const float prc = rowc[pi];
    const float prm = rmax[pi];
    const int   prv = rvv[pi];
    float zacc = 0.f;

    const size_t obase = (size_t)b * OUTD * Ee;
    const int o0 = w * 64;

    floatx4 acc[4][4];
    #pragma unroll
    for (int i = 0; i < 4; ++i)
        #pragma unroll
        for (int j = 0; j < 4; ++j)
            acc[i][j] = (floatx4)0.f;

    for (int ks = 0; ks < 16; ++ks) {
        const int k0  = ks * 32;
        const int buf = ks & 1;

        half8 ph;
        #pragma unroll
        for (int kk = 0; kk < 8; ++kk) {
            const int j = k0 + pj + kk;
            float pv;
            if (prv) {
                float sc = prc + s2v[j];
                sc = (sc >= 0.f) ? sc : LRELU * sc;
                pv = (mkv[j] > 0.f) ? __expf(sc - prm) : 0.f;
            } else {
                pv = 1.f;
            }
            const _Float16 hq = (_Float16)pv;
            ph[kk] = hq;
            zacc += (float)hq;
        }
        *reinterpret_cast<half8*>(&Pl[buf][pi][pj]) = ph;

        half8 bh[4];
        #pragma unroll
        for (int ot = 0; ot < 4; ++ot) {
            const size_t ro = obase + (size_t)(o0 + ot * 16 + ln) * Ee + k0 + lg * 8;
            bh[ot] = *reinterpret_cast<const half8*>(&HmTh[ro]);
        }
        __syncthreads();

        half8 af[4];
        #pragma unroll
        for (int mr = 0; mr < 4; ++mr)
            af[mr] = *reinterpret_cast<const half8*>(&Pl[buf][mr * 16 + ln][lg * 8]);
        #pragma unroll
        for (int mr = 0; mr < 4; ++mr)
            #pragma unroll
            for (int ot = 0; ot < 4; ++ot)
                acc[mr][ot] = __builtin_amdgcn_mfma_f32_16x16x32_f16(
                    af[mr], bh[ot], acc[mr][ot], 0, 0, 0);
    }

    Zp[pi][t & 3] = zacc;
    __syncthreads();
    if (t < 64) {
        const float z = Zp[t][0] + Zp[t][1] + Zp[t][2] + Zp[t][3];
        zr[t] = 1.f / z;
    }
    __syncthreads();

    float* __restrict__ Ob = Out + ((size_t)b * Ee + i0) * OUTD;
    #pragma unroll
    for (int mr = 0; mr < 4; ++mr)
        #pragma unroll
        for (int rr = 0; rr < 4; ++rr) {
            const int i = mr * 16 + lg * 4 + rr;
            const float rzi = zr[i];
            #pragma unroll
            for (int ot = 0; ot < 4; ++ot)
                Ob[(size_t)i * OUTD + o0 + ot * 16 + ln] = acc[mr][ot][rr] * rzi;
        }
}

extern "C" void kernel_launch(void* const* d_in, const int* in_sizes, int n_in,
                              void* d_out, int out_size, void* d_ws, size_t ws_size,
                              hipStream_t stream) {
    const float* X    = (const float*)d_in[0];
    // d_in[1] = adj : unused by the reference (dead input)
    const int*   mask = (const int*)d_in[2];
    const float* Ww   = (const float*)d_in[3];
    const float* Wb   = (const float*)d_in[4];
    const float* aw   = (const float*)d_in[5];
    const float* ab   = (const float*)d_in[6];
    float* out = (float*)d_out;

    _Float16* HmTh = (_Float16*)d_ws;                     // [64][256][512] fp16 = 16 MB
    float* s1 = (float*)(HmTh + (size_t)Bb * OUTD * Ee);  // 128 KB
    float* s2 = s1 + Mrows;                               // 128 KB
    _Float16* Whf = (_Float16*)(s2 + Mrows);              // 512 KB

    wconv_kernel<<<OUTD * IND / (256 * 4), 256, 0, stream>>>(Ww, Whf);
    gemm_h_f16<<<Mrows / 64, 256, 0, stream>>>(X, Whf, Wb, aw, mask, HmTh, s1, s2);
    attn_mfma<<<Bb * (Ee / 64), 256, 0, stream>>>(HmTh, s1, s2, mask, ab, out);
}